// Round 1
// baseline (425.466 us; speedup 1.0000x reference)
//
#include <hip/hip_runtime.h>
#include <hip/hip_bf16.h>

#define NN      100000
#define DF      64
#define NPB     32          // nodes per block; NN % NPB == 0 -> 3125 blocks
#define CHUNK   64          // edges per chunk (4 waves x 16 edges)

typedef __bf16 bf16x8 __attribute__((ext_vector_type(8)));
typedef float  f32x4  __attribute__((ext_vector_type(4)));

// tanh-approx gelu written as x * sigmoid(2u), u = 0.79788456*(x + 0.044715 x^3)
__device__ __forceinline__ float gelu_f(float x) {
    float u2 = x * (1.5957691216057308f + 0.07135481627f * x * x);
    float s  = __expf(-u2);
    return __fdividef(x, 1.0f + s);
}

__global__ __launch_bounds__(256, 2)
void it_fused(const float* __restrict__ y, const float* __restrict__ fy,
              const float* __restrict__ W0, const float* __restrict__ b0,
              const float* __restrict__ W1, const float* __restrict__ b1,
              const int* __restrict__ nbr, const int* __restrict__ splits,
              float* __restrict__ out)
{
    __shared__ int   splitsL[NPB + 1];
    __shared__ float nodeacc[NPB][DF];
    __shared__ float aggL[CHUNK][6];
    __shared__ int   nbrL[CHUNK];
    __shared__ int   segL[CHUNK];

    const int t  = threadIdx.x;
    const int n0 = blockIdx.x * NPB;

    if (t <= NPB) splitsL[t] = splits[n0 + t];
    for (int i = t; i < NPB * DF; i += 256) ((float*)nodeacc)[i] = 0.0f;
    __syncthreads();

    const int e_begin = splitsL[0];
    const int e_end   = splitsL[NPB];

    const int lane = t & 63;
    const int wv   = t >> 6;
    const int col  = lane & 15;   // MFMA N-index / A-row index
    const int kg   = lane >> 4;   // MFMA K-group

    // ---- hoisted constants (per-lane slices, loaded once per block, L1/L2-served) ----
    float w0r[2][8][6];
    float b0r[2][8];
    #pragma unroll
    for (int kf = 0; kf < 2; kf++)
        #pragma unroll
        for (int j = 0; j < 8; j++) {
            const int c = kf * 32 + kg * 8 + j;
            #pragma unroll
            for (int k = 0; k < 6; k++) w0r[kf][j][k] = W0[k * DF + c];
            b0r[kf][j] = b0[c];
        }
    float  b1r[4];
    bf16x8 bfrag[4][2];   // W1 B-fragments: B[k=(kf*32+kg*8+j)][n=nt*16+col]
    #pragma unroll
    for (int nt = 0; nt < 4; nt++) {
        b1r[nt] = b1[nt * 16 + col];
        #pragma unroll
        for (int kf = 0; kf < 2; kf++)
            #pragma unroll
            for (int j = 0; j < 8; j++)
                bfrag[nt][kf][j] = (__bf16)W1[(kf * 32 + kg * 8 + j) * DF + nt * 16 + col];
    }

    const int nchunks = (e_end - e_begin + CHUNK - 1) / CHUNK;

    for (int chk = 0; chk < nchunks; chk++) {
        const int ebase = e_begin + chk * CHUNK;

        // ---- Phase A: per-edge staging (first wave only) ----
        if (t < CHUNK) {
            const int e = ebase + t;
            int nb = 0, sg = 0;
            float a0 = 0.f, a1 = 0.f, a2 = 0.f, a3 = 0.f, a4 = 0.f, a5 = 0.f;
            if (e < e_end) {
                nb = nbr[e];
                int s = 0;
                #pragma unroll
                for (int i = 1; i <= NPB; i++) s += (splitsL[i] <= e) ? 1 : 0;
                sg = s;                       // local segment id 0..NPB-1
                a0 = y[nb * 3 + 0]; a1 = y[nb * 3 + 1]; a2 = y[nb * 3 + 2];
                const int gs = n0 + s;
                a3 = y[gs * 3 + 0]; a4 = y[gs * 3 + 1]; a5 = y[gs * 3 + 2];
            }
            aggL[t][0] = a0; aggL[t][1] = a1; aggL[t][2] = a2;
            aggL[t][3] = a3; aggL[t][4] = a4; aggL[t][5] = a5;
            nbrL[t] = nb; segL[t] = sg;
        }
        __syncthreads();

        // ---- Phase B: h0 = gelu(agg@W0+b0), built directly in A-fragment layout ----
        const int erow = wv * 16 + col;     // this lane's A-row edge (within chunk)
        const float g0 = aggL[erow][0], g1 = aggL[erow][1], g2 = aggL[erow][2],
                    g3 = aggL[erow][3], g4 = aggL[erow][4], g5 = aggL[erow][5];

        bf16x8 af[2];
        #pragma unroll
        for (int kf = 0; kf < 2; kf++)
            #pragma unroll
            for (int j = 0; j < 8; j++) {
                float h = b0r[kf][j];
                h += g0 * w0r[kf][j][0]; h += g1 * w0r[kf][j][1];
                h += g2 * w0r[kf][j][2]; h += g3 * w0r[kf][j][3];
                h += g4 * w0r[kf][j][4]; h += g5 * w0r[kf][j][5];
                af[kf][j] = (__bf16)gelu_f(h);
            }

        // ---- Phase C: h1 = h0 @ W1  (fp32 accum) ----
        f32x4 acc[4] = {};
        #pragma unroll
        for (int nt = 0; nt < 4; nt++) {
            acc[nt] = __builtin_amdgcn_mfma_f32_16x16x32_bf16(af[0], bfrag[nt][0], acc[nt], 0, 0, 0);
            acc[nt] = __builtin_amdgcn_mfma_f32_16x16x32_bf16(af[1], bfrag[nt][1], acc[nt], 0, 0, 0);
        }

        // ---- Phase D/E: gate by f_y[nbr], segmented-reduce into LDS node accumulators ----
        const int equad = wv * 16 + kg * 4;   // first edge of this lane's D-row quad
        const int s0 = segL[equad + 0], s1 = segL[equad + 1],
                  s2 = segL[equad + 2], s3 = segL[equad + 3];
        const int nb0 = nbrL[equad + 0], nb1 = nbrL[equad + 1],
                  nb2 = nbrL[equad + 2], nb3 = nbrL[equad + 3];
        const int rem = e_end - (ebase + equad);   // reg r valid iff r < rem
        #pragma unroll
        for (int nt = 0; nt < 4; nt++) {
            const int   c  = nt * 16 + col;
            const float bb = b1r[nt];
            float v0 = (0 < rem) ? (acc[nt][0] + bb) * fy[nb0 * DF + c] : 0.0f;
            float v1 = (1 < rem) ? (acc[nt][1] + bb) * fy[nb1 * DF + c] : 0.0f;
            float v2 = (2 < rem) ? (acc[nt][2] + bb) * fy[nb2 * DF + c] : 0.0f;
            float v3 = (3 < rem) ? (acc[nt][3] + bb) * fy[nb3 * DF + c] : 0.0f;
            if (s0 == s3) {   // monotone -> all four equal: merged single LDS atomic
                unsafeAtomicAdd(&nodeacc[s0][c], ((v0 + v1) + (v2 + v3)));
            } else {
                unsafeAtomicAdd(&nodeacc[s0][c], v0);
                unsafeAtomicAdd(&nodeacc[s1][c], v1);
                unsafeAtomicAdd(&nodeacc[s2][c], v2);
                unsafeAtomicAdd(&nodeacc[s3][c], v3);
            }
        }
        __syncthreads();   // protects aggL/nbrL/segL reuse + orders LDS atomics
    }

    // ---- Epilogue: mean and store (each node owned by exactly this block) ----
    for (int i = t; i < NPB * DF; i += 256) {
        const int node = i >> 6;
        const int cnt  = splitsL[node + 1] - splitsL[node];
        const float inv = (cnt > 0) ? __fdividef(1.0f, (float)cnt) : 0.0f;
        out[n0 * DF + i] = ((float*)nodeacc)[i] * inv;
    }
}

extern "C" void kernel_launch(void* const* d_in, const int* in_sizes, int n_in,
                              void* d_out, int out_size, void* d_ws, size_t ws_size,
                              hipStream_t stream) {
    const float* y   = (const float*)d_in[0];
    const float* fyv = (const float*)d_in[1];
    const float* W0  = (const float*)d_in[2];
    const float* b0  = (const float*)d_in[3];
    const float* W1  = (const float*)d_in[4];
    const float* b1  = (const float*)d_in[5];
    const int*   nb  = (const int*)d_in[6];   // harness delivers integer inputs as int32
    const int*   sp  = (const int*)d_in[7];
    it_fused<<<NN / NPB, 256, 0, stream>>>(y, fyv, W0, b0, W1, b1, nb, sp, (float*)d_out);
}